// Round 10
// baseline (231.266 us; speedup 1.0000x reference)
//
#include <hip/hip_runtime.h>
#include <hip/hip_bf16.h>

// HeteroGAT: 2-relation GAT, N=100000, IN=OUT=128, E=320000/rel.
// Dtypes (R1-R4 verified): inputs f32, output f32.
// R17: 229.3us, fused gemm+rank 68.5us -- discriminator fired. NR doubling
// did NOT shorten rank blocks (each still scans its FULL chunk; only the
// filter narrowed), so long-lived scan blocks again poisoned gemm (29->68).
// R18: standalone rank with correct geometry -- NP=8 x NR=64 x 2rels = 1024
// blocks, chunk 40K (39 int4-iters), hist 1563 bins = 6.3KB LDS, 16
// waves/CU. Scan traffic 164MB L2-resident ~= 5us. scanA converts partial
// to per-node exclusive prefixes IN-PLACE so fill needs exactly ONE offset
// gather. rowptr[n2] = 2E constant. gemm reverts to pure R16 form (~29us).
// 7 dispatches, zero global atomics.

typedef __bf16 bf16x8 __attribute__((ext_vector_type(8)));
typedef float f32x4 __attribute__((ext_vector_type(4)));

#define DIM 128
#define NP 8                       // edge-list partitions
#define NR 64                      // dst ranges per rel
#define RANK_BLOCKS (NP * NR * 2)  // 1024
#define HIST_BINS 1568             // 6272B LDS; rngsz=1563 fits

// ---- prep: W^T (both rels) -> bf16 in exact B-fragment order ----
// entry e = ((rel*8 + ct)*4 + ko4)*64 + lane holds 8 bf16:
//   B[k = ko4*32 + (lane>>4)*8 + j][n = ct*16 + (lane&15)], j=0..7
__global__ __launch_bounds__(256) void prep_w_kernel(
    const float* __restrict__ W0, const float* __restrict__ W1,
    __bf16* __restrict__ wtf)
{
    const int e = blockIdx.x * 256 + threadIdx.x;   // 4096 entries
    if (e >= 4096) return;
    const int lane = e & 63;
    const int ko4  = (e >> 6) & 3;
    const int ct   = (e >> 8) & 7;
    const int rel  = e >> 11;
    const float* W = rel ? W1 : W0;
    const int n  = ct * 16 + (lane & 15);
    const int k0 = ko4 * 32 + (lane >> 4) * 8;
    bf16x8 v;
#pragma unroll
    for (int j = 0; j < 8; ++j) v[j] = (__bf16)W[(k0 + j) * DIM + n];
    *(bf16x8*)(wtf + (size_t)e * 8) = v;
}

// ---- standalone rank builder: LDS histograms, zero global atomics ----
// Block (p = bid&7, r = bid>>3): scans edge chunk p (40K edges, 39 int4
// iters) of rel (r>>6)'s dst array; nodes in range (r&63) get rank =
// LDS-hist++ (DS atomic, CU-local). Histogram dumped via plain coalesced
// stores into partial[p][rel*N+node]. 1024 blocks, 6.3KB LDS -> 16 waves/CU.
// dst arrays (1.28MB/rel) stay L2-resident across the 64x re-scan.
__global__ __launch_bounds__(256) void rank_hist_kernel(
    const int* __restrict__ dst0, const int* __restrict__ dst1,
    unsigned* __restrict__ partial, unsigned* __restrict__ rank,
    int N, int E)
{
    __shared__ unsigned hist_[HIST_BINS];
    const int tid = threadIdx.x;
    const int p    = blockIdx.x & (NP - 1);
    const int r    = blockIdx.x >> 3;          // [0,128)
    const int rel  = r >> 6;
    const int rr   = r & (NR - 1);
    const int rngsz = (N + NR - 1) / NR;       // 1563
    const int lo = rr * rngsz;
    const int hi = min(lo + rngsz, N);
    const int nbins = hi - lo;
    if (nbins <= 0) return;
    for (int j = tid; j < nbins; j += 256) hist_[j] = 0u;
    __syncthreads();

    const int chunk = (E + NP - 1) / NP;       // 40000
    const int e0 = p * chunk;
    const int e1 = min(e0 + chunk, E);
    const int* dsts = rel ? dst1 : dst0;
    unsigned* rk = rank + (rel ? E : 0);

    for (int i = e0 + tid * 4; i < e1; i += 1024) {
        if (i + 3 < e1) {
            const int4 v = *(const int4*)(dsts + i);
            if (v.x >= lo && v.x < hi) rk[i]     = atomicAdd(&hist_[v.x - lo], 1u);
            if (v.y >= lo && v.y < hi) rk[i + 1] = atomicAdd(&hist_[v.y - lo], 1u);
            if (v.z >= lo && v.z < hi) rk[i + 2] = atomicAdd(&hist_[v.z - lo], 1u);
            if (v.w >= lo && v.w < hi) rk[i + 3] = atomicAdd(&hist_[v.w - lo], 1u);
        } else {
            for (int j = i; j < e1; ++j) {
                const int d = dsts[j];
                if (d >= lo && d < hi) rk[j] = atomicAdd(&hist_[d - lo], 1u);
            }
        }
    }
    __syncthreads();
    unsigned* part = partial + (size_t)p * (2 * N) + (size_t)rel * N + lo;
    for (int j = tid; j < nbins; j += 256) part[j] = hist_[j];
}

// ---- wh_r = bf16(x) @ W_r + b_r (both rels) -- PURE, no edge work ----
// Block 256 = 4 waves; wave owns 16 rows; block 64 rows. No LDS for W:
// bfrags are wave-uniform coalesced 1KB global loads from wtf (L1-hit).
// x read once per block (both rels share the A-slice in VGPRs).
__global__ __launch_bounds__(256) void gemm_wh_kernel(
    const float* __restrict__ x, const __bf16* __restrict__ wtf,
    const float* __restrict__ b0, const float* __restrict__ b1,
    const float* __restrict__ a0, const float* __restrict__ a1,
    __bf16* __restrict__ wh, float* __restrict__ s_src,
    float* __restrict__ s_dst, int N)
{
    __shared__ __align__(16) __bf16 Cst[64 * 136];  // 17408 B C-staging
    const int tid = threadIdx.x;

    const int lane = tid & 63;
    const int wave = tid >> 6;
    const int quad = lane >> 4;
    const int mr   = lane & 15;

    const long row0 = (long)blockIdx.x * 64 + wave * 16;
    long arow = row0 + mr;
    if (arow >= N) arow = N - 1;               // clamp; results discarded
    const f32x4* xr = (const f32x4*)(x + arow * DIM);

    // full A slice for this lane: k = ko4*32 + quad*8 .. +7
    bf16x8 afrag[4];
#pragma unroll
    for (int ko4 = 0; ko4 < 4; ++ko4) {
        f32x4 lo = xr[ko4 * 8 + quad * 2], hi = xr[ko4 * 8 + quad * 2 + 1];
        afrag[ko4] = (bf16x8){ (__bf16)lo.x, (__bf16)lo.y, (__bf16)lo.z, (__bf16)lo.w,
                               (__bf16)hi.x, (__bf16)hi.y, (__bf16)hi.z, (__bf16)hi.w };
    }

    const bf16x8* wt = (const bf16x8*)wtf;

#pragma unroll
    for (int rel = 0; rel < 2; ++rel) {
        f32x4 zero = {0.f, 0.f, 0.f, 0.f};
        f32x4 acc[8];
#pragma unroll
        for (int t = 0; t < 8; ++t) acc[t] = zero;

#pragma unroll
        for (int ko4 = 0; ko4 < 4; ++ko4) {
#pragma unroll
            for (int ct = 0; ct < 8; ++ct) {
                bf16x8 bfrag = wt[((rel * 8 + ct) * 4 + ko4) * 64 + lane];
                acc[ct] = __builtin_amdgcn_mfma_f32_16x16x32_bf16(afrag[ko4], bfrag, acc[ct], 0, 0, 0);
            }
        }

        const float* bias = rel ? b1 : b0;
        const float* a    = rel ? a1 : a0;
        // C/D layout: col = ct*16+mr, row = quad*4+rr [m89-verified]
        float psr[4] = {0.f, 0.f, 0.f, 0.f};
        float pdr[4] = {0.f, 0.f, 0.f, 0.f};
#pragma unroll
        for (int ct = 0; ct < 8; ++ct) {
            const int c = ct * 16 + mr;
            const float bn = bias[c];
            const float asc = a[c], adc = a[DIM + c];
#pragma unroll
            for (int rr = 0; rr < 4; ++rr) {
                const float wv = acc[ct][rr] + bn;
                Cst[(wave * 16 + quad * 4 + rr) * 136 + c] = (__bf16)wv;
                psr[rr] += asc * wv;
                pdr[rr] += adc * wv;
            }
        }
#pragma unroll
        for (int off = 1; off < 16; off <<= 1) {
#pragma unroll
            for (int rr = 0; rr < 4; ++rr) {
                psr[rr] += __shfl_xor(psr[rr], off);
                pdr[rr] += __shfl_xor(pdr[rr], off);
            }
        }
        if (mr == 0) {
#pragma unroll
            for (int rr = 0; rr < 4; ++rr) {
                const long orow = row0 + quad * 4 + rr;
                if (orow < N) {
                    s_src[(size_t)rel * N + orow] = psr[rr];
                    s_dst[(size_t)rel * N + orow] = pdr[rr];
                }
            }
        }
        __syncthreads();                        // staging complete
        // coalesced read-back: 1024 chunks of 16B
#pragma unroll
        for (int i = 0; i < 4; ++i) {
            const int chunk = tid + 256 * i;
            const int row = chunk >> 4, c8 = chunk & 15;
            bf16x8 v = *(const bf16x8*)&Cst[row * 136 + c8 * 8];
            const long grow = (long)blockIdx.x * 64 + row;
            if (grow < N)
                *(bf16x8*)(wh + ((size_t)rel * N + grow) * DIM + c8 * 8) = v;
        }
        __syncthreads();                        // before rel1 re-stages Cst
    }
}

// ---------------- CSR scan pass 1 + in-place partial prefix ----------------
// deg[i] = sum of the NP partials; simultaneously rewrites partial[p][i]
// to the EXCLUSIVE prefix sum over p (so fill needs one gather, not p).
__global__ __launch_bounds__(256) void scanA_kernel(
    unsigned* __restrict__ partial, unsigned* __restrict__ tmp,
    unsigned* __restrict__ bsum, int n)
{
    __shared__ unsigned s[256];
    const int t = threadIdx.x;
    const int i = blockIdx.x * 256 + t;
    unsigned v = 0u;
    if (i < n) {
        unsigned run = 0u;
#pragma unroll
        for (int p = 0; p < NP; ++p) {
            const unsigned c = partial[(size_t)p * n + i];
            partial[(size_t)p * n + i] = run;
            run += c;
        }
        v = run;
    }
    s[t] = v;
    __syncthreads();
#pragma unroll
    for (int off = 1; off < 256; off <<= 1) {
        unsigned add = (t >= off) ? s[t - off] : 0u;
        __syncthreads();
        s[t] += add;
        __syncthreads();
    }
    if (i < n) tmp[i] = s[t] - v;            // exclusive within block
    if (t == 255) bsum[blockIdx.x] = s[t];   // block total
}

// ---- CSR scan pass 2: each block re-scans bsum locally, writes rowptr ----
// nb <= 1024 (782 here); rowptr[n] = total (2E) constant.
__global__ __launch_bounds__(256) void scan2_kernel(
    const unsigned* __restrict__ tmp, const unsigned* __restrict__ bsum,
    unsigned* __restrict__ rowptr, int n, int nb, unsigned total)
{
    __shared__ unsigned s[256];
    __shared__ unsigned ex[1024];
    const int t = threadIdx.x;
    unsigned loc[4], sum = 0u;
#pragma unroll
    for (int k = 0; k < 4; ++k) {
        int idx = t * 4 + k;
        loc[k] = (idx < nb) ? bsum[idx] : 0u;
        sum += loc[k];
    }
    s[t] = sum;
    __syncthreads();
#pragma unroll
    for (int off = 1; off < 256; off <<= 1) {
        unsigned add = (t >= off) ? s[t - off] : 0u;
        __syncthreads();
        s[t] += add;
        __syncthreads();
    }
    unsigned run = s[t] - sum;
#pragma unroll
    for (int k = 0; k < 4; ++k) {
        ex[t * 4 + k] = run;
        run += loc[k];
    }
    __syncthreads();
    const unsigned pref = ex[blockIdx.x];
    const int i = blockIdx.x * 256 + t;
    if (i < n) {
        rowptr[i] = tmp[i] + pref;
        if (i == n - 1) rowptr[n] = total;
    }
}

// ---- CSR build + edge scores: fully atomic-free streaming ----
// slot = rowptr[dst] + partial_prefix[p][dst] + local rank (ONE offset
// gather; partial holds exclusive prefixes after scanA). Chain stays
// independent loads -> expf -> fire-and-forget store.
__global__ __launch_bounds__(256) void fill_kernel(
    const int* __restrict__ src0, const int* __restrict__ dst0,
    const int* __restrict__ src1, const int* __restrict__ dst1,
    const float* __restrict__ s_src, const float* __restrict__ s_dst,
    const unsigned* __restrict__ rowptr, const unsigned* __restrict__ rank,
    const unsigned* __restrict__ partial,
    uint2* __restrict__ sorted, int N, int E)
{
    const int i = blockIdx.x * 256 + threadIdx.x;
    if (i >= E) return;
    const int s0 = src0[i], d0 = dst0[i];
    const int s1 = src1[i], d1 = dst1[i];

    const int chunk = (E + NP - 1) / NP;
    const int p = i / chunk;
    const int n2 = 2 * N;
    const unsigned off0 = partial[(size_t)p * n2 + d0];
    const unsigned off1 = partial[(size_t)p * n2 + N + d1];
    const unsigned p0 = rowptr[d0] + off0 + rank[i];
    const unsigned p1 = rowptr[N + d1] + off1 + rank[E + i];

    float v0 = s_src[s0] + s_dst[d0];
    v0 = v0 > 0.f ? v0 : 0.01f * v0;            // leaky_relu slope 0.01
    const float e0 = __expf(v0);
    float v1 = s_src[N + s1] + s_dst[N + d1];
    v1 = v1 > 0.f ? v1 : 0.01f * v1;
    const float e1 = __expf(v1);

    sorted[p0] = make_uint2((unsigned)s0, __float_as_uint(e0));
    sorted[p1] = make_uint2((unsigned)s1, __float_as_uint(e1));
}

// ---------------- gather-sum with inline softmax denominators ----------------
// One wave per dst. Both rels merged into one virtual edge list (len T);
// 4 subgroups x 2 slots = 8 edges in flight per round. Branchless: invalid
// slots clamp idx to 0 (L1-hit dummy row) with weight 0. Per-rel unnormalized
// accumulators a0/a1 + denominators l0/l1 built inline (rel select via zeroed
// weights); single cross-subgroup combine of 18 values, normalize, write.
__global__ __launch_bounds__(256) void aggregate_kernel(
    const unsigned* __restrict__ rowptr, const uint2* __restrict__ sorted,
    const __bf16* __restrict__ wh, float* __restrict__ out, int N)
{
    const int tid  = threadIdx.x;
    const int lane = tid & 63;
    const int sub  = lane >> 4;
    const int mr   = lane & 15;
    int d = blockIdx.x * 4 + (tid >> 6);
    if (d >= N) return;
    d = __builtin_amdgcn_readfirstlane(d);      // wave-uniform -> s_loads

    const unsigned beg0 = rowptr[d],     end0 = rowptr[d + 1];
    const unsigned beg1 = rowptr[N + d], end1 = rowptr[N + d + 1];
    const unsigned len0 = end0 - beg0;
    const unsigned T    = len0 + (end1 - beg1);

    float acc0[8], acc1[8], l0 = 0.f, l1 = 0.f;
#pragma unroll
    for (int k = 0; k < 8; ++k) { acc0[k] = 0.f; acc1[k] = 0.f; }

    const size_t whstride = (size_t)N * DIM;

    for (unsigned t0 = 0; t0 < T; t0 += 8) {
        const unsigned tA = t0 + sub, tB = tA + 4;
        const bool vA = tA < T, vB = tB < T;
        const bool rA = tA >= len0, rB = tB >= len0;

        unsigned iA = rA ? beg1 + (tA - len0) : beg0 + tA;
        unsigned iB = rB ? beg1 + (tB - len0) : beg0 + tB;
        iA = vA ? iA : 0u;
        iB = vB ? iB : 0u;

        const uint2 eA = sorted[iA];
        const uint2 eB = sorted[iB];

        const float evA = vA ? __uint_as_float(eA.y) : 0.f;
        const float evB = vB ? __uint_as_float(eB.y) : 0.f;
        const float wA0 = rA ? 0.f : evA, wA1 = rA ? evA : 0.f;
        const float wB0 = rB ? 0.f : evB, wB1 = rB ? evB : 0.f;
        l0 += wA0 + wB0;
        l1 += wA1 + wB1;

        const bf16x8 wA = *(const bf16x8*)(wh + (rA ? whstride : 0)
                                              + (size_t)eA.x * DIM + mr * 8);
        const bf16x8 wB = *(const bf16x8*)(wh + (rB ? whstride : 0)
                                              + (size_t)eB.x * DIM + mr * 8);
#pragma unroll
        for (int k = 0; k < 8; ++k) {
            const float fA = (float)wA[k], fB = (float)wB[k];
            acc0[k] += wA0 * fA + wB0 * fB;
            acc1[k] += wA1 * fA + wB1 * fB;
        }
    }

    // single combine across 4 subgroups (16+2 values)
#pragma unroll
    for (int k = 0; k < 8; ++k) {
        acc0[k] += __shfl_xor(acc0[k], 16);
        acc0[k] += __shfl_xor(acc0[k], 32);
        acc1[k] += __shfl_xor(acc1[k], 16);
        acc1[k] += __shfl_xor(acc1[k], 32);
    }
    l0 += __shfl_xor(l0, 16); l0 += __shfl_xor(l0, 32);
    l1 += __shfl_xor(l1, 16); l1 += __shfl_xor(l1, 32);

    const float inv0 = l0 > 0.f ? 1.f / l0 : 0.f;
    const float inv1 = l1 > 0.f ? 1.f / l1 : 0.f;

    if (sub == 0) {                             // 16 lanes cover the 512B row
        float o[8];
#pragma unroll
        for (int k = 0; k < 8; ++k) o[k] = acc0[k] * inv0 + acc1[k] * inv1;
        float4 v0 = {o[0], o[1], o[2], o[3]};
        float4 v1 = {o[4], o[5], o[6], o[7]};
        float* op = out + (size_t)d * DIM + mr * 8;
        *(float4*)op       = v0;
        *(float4*)(op + 4) = v1;
    }
}

extern "C" void kernel_launch(void* const* d_in, const int* in_sizes, int n_in,
                              void* d_out, int out_size, void* d_ws, size_t ws_size,
                              hipStream_t stream) {
    const float* x = (const float*)d_in[0];
    const int* srcs[2] = {(const int*)d_in[1], (const int*)d_in[3]};
    const int* dsts[2] = {(const int*)d_in[2], (const int*)d_in[4]};
    const float* Ws[2] = {(const float*)d_in[5], (const float*)d_in[8]};
    const float* Bs[2] = {(const float*)d_in[6], (const float*)d_in[9]};
    const float* As[2] = {(const float*)d_in[7], (const float*)d_in[10]};

    const int N = in_sizes[0] / DIM;
    const int E = in_sizes[1];
    const int n2 = 2 * N;
    const int nb = (n2 + 255) / 256;            // scan blocks (782)
    float* out = (float*)d_out;

    // workspace carve-up (~70 MB); all chunks 8B-aligned
    char* p = (char*)d_ws;
    __bf16*   wh      = (__bf16*)p;   p += (size_t)n2 * DIM * 2;       // wh0|wh1
    __bf16*   wtf     = (__bf16*)p;   p += (size_t)4096 * 8 * 2;       // 64KB frag-W
    float*    s_src   = (float*)p;    p += (size_t)n2 * 4;
    float*    s_dst   = (float*)p;    p += (size_t)n2 * 4;
    unsigned* partial = (unsigned*)p; p += (size_t)NP * n2 * 4;        // 6.4MB hists
    unsigned* tmp     = (unsigned*)p; p += (size_t)n2 * 4;
    unsigned* rowptr  = (unsigned*)p; p += (size_t)(n2 + 2) * 4;       // pad to 8B
    unsigned* rank    = (unsigned*)p; p += (size_t)2 * E * 4;          // per-edge rank
    uint2*    sorted  = (uint2*)p;    p += (size_t)2 * E * 8;          // {src, e}
    unsigned* bsum    = (unsigned*)p; p += (size_t)nb * 4;

    prep_w_kernel<<<16, 256, 0, stream>>>(Ws[0], Ws[1], wtf);
    rank_hist_kernel<<<RANK_BLOCKS, 256, 0, stream>>>(
        dsts[0], dsts[1], partial, rank, N, E);
    gemm_wh_kernel<<<(N + 63) / 64, 256, 0, stream>>>(
        x, wtf, Bs[0], Bs[1], As[0], As[1], wh, s_src, s_dst, N);
    scanA_kernel<<<nb, 256, 0, stream>>>(partial, tmp, bsum, n2);
    scan2_kernel<<<nb, 256, 0, stream>>>(tmp, bsum, rowptr, n2, nb,
                                         (unsigned)(2 * E));
    fill_kernel<<<(E + 255) / 256, 256, 0, stream>>>(
        srcs[0], dsts[0], srcs[1], dsts[1], s_src, s_dst,
        rowptr, rank, partial, sorted, N, E);
    aggregate_kernel<<<(N + 3) / 4, 256, 0, stream>>>(
        rowptr, sorted, wh, out, N);
}

// Round 11
// 229.136 us; speedup vs baseline: 1.0093x; 1.0093x over previous
//
#include <hip/hip_runtime.h>
#include <hip/hip_bf16.h>

// HeteroGAT: 2-relation GAT, N=100000, IN=OUT=128, E=320000/rel.
// Dtypes (R1-R4 verified): inputs f32, output f32.
// R18: 231.3us; rank/gemm fixed (both out of top-5), aggregate top again at
// 49.5us: VALUBusy 73% -> near VALU-bound; dual per-rel accumulators waste
// half their FMAs (each edge is in exactly one rel) because inv0/inv1 are
// only known post-loop. R19: two-pass aggregate -- pass 1 computes l0/l1
// via coalesced lane-per-edge reads of sorted[].y + wave reduce (DS pipe),
// pass 2 gathers with PRE-normalized weights into a SINGLE accumulator
// (16 FMA/round vs 32, epilogue halved, no final normalize). sorted L1-hot
// for pass 2. prep_w folded into the rank_hist dispatch. 6 dispatches,
// zero global atomics.

typedef __bf16 bf16x8 __attribute__((ext_vector_type(8)));
typedef float f32x4 __attribute__((ext_vector_type(4)));

#define DIM 128
#define NP 8                       // edge-list partitions
#define NR 64                      // dst ranges per rel
#define RANK_BLOCKS (NP * NR * 2)  // 1024
#define HIST_BINS 1568             // 6272B LDS; rngsz=1563 fits

// ---- fused: rank-histogram blocks + W-fragment prep blocks ----
// Rank role (bid < RANK_BLOCKS): block (p = bid&7, r = bid>>3) scans edge
// chunk p (40K edges, 39 int4 iters) of rel (r>>6)'s dst array; nodes in
// range (r&63) get rank = LDS-hist++ (DS atomic, CU-local). Histogram
// dumped via plain coalesced stores into partial[p][rel*N+node]. 6.3KB LDS
// -> high co-residency; dst arrays (1.28MB/rel) L2-resident across the 64x
// re-scan. Prep role (last 16 blocks): W^T (both rels) -> bf16 in exact
// B-fragment order: entry e = ((rel*8+ct)*4+ko4)*64+lane holds
// B[k = ko4*32+(lane>>4)*8+j][n = ct*16+(lane&15)], j=0..7.
__global__ __launch_bounds__(256) void rank_prep_kernel(
    const int* __restrict__ dst0, const int* __restrict__ dst1,
    unsigned* __restrict__ partial, unsigned* __restrict__ rank,
    const float* __restrict__ W0, const float* __restrict__ W1,
    __bf16* __restrict__ wtf, int N, int E)
{
    __shared__ unsigned hist_[HIST_BINS];
    const int tid = threadIdx.x;

    if (blockIdx.x >= RANK_BLOCKS) {            // prep role
        const int e = (blockIdx.x - RANK_BLOCKS) * 256 + tid;  // 4096 entries
        if (e >= 4096) return;
        const int lane = e & 63;
        const int ko4  = (e >> 6) & 3;
        const int ct   = (e >> 8) & 7;
        const int rel  = e >> 11;
        const float* W = rel ? W1 : W0;
        const int n  = ct * 16 + (lane & 15);
        const int k0 = ko4 * 32 + (lane >> 4) * 8;
        bf16x8 v;
#pragma unroll
        for (int j = 0; j < 8; ++j) v[j] = (__bf16)W[(k0 + j) * DIM + n];
        *(bf16x8*)(wtf + (size_t)e * 8) = v;
        return;
    }

    const int p    = blockIdx.x & (NP - 1);
    const int r    = blockIdx.x >> 3;          // [0,128)
    const int rel  = r >> 6;
    const int rr   = r & (NR - 1);
    const int rngsz = (N + NR - 1) / NR;       // 1563
    const int lo = rr * rngsz;
    const int hi = min(lo + rngsz, N);
    const int nbins = hi - lo;
    if (nbins <= 0) return;
    for (int j = tid; j < nbins; j += 256) hist_[j] = 0u;
    __syncthreads();

    const int chunk = (E + NP - 1) / NP;       // 40000
    const int e0 = p * chunk;
    const int e1 = min(e0 + chunk, E);
    const int* dsts = rel ? dst1 : dst0;
    unsigned* rk = rank + (rel ? E : 0);

    for (int i = e0 + tid * 4; i < e1; i += 1024) {
        if (i + 3 < e1) {
            const int4 v = *(const int4*)(dsts + i);
            if (v.x >= lo && v.x < hi) rk[i]     = atomicAdd(&hist_[v.x - lo], 1u);
            if (v.y >= lo && v.y < hi) rk[i + 1] = atomicAdd(&hist_[v.y - lo], 1u);
            if (v.z >= lo && v.z < hi) rk[i + 2] = atomicAdd(&hist_[v.z - lo], 1u);
            if (v.w >= lo && v.w < hi) rk[i + 3] = atomicAdd(&hist_[v.w - lo], 1u);
        } else {
            for (int j = i; j < e1; ++j) {
                const int d = dsts[j];
                if (d >= lo && d < hi) rk[j] = atomicAdd(&hist_[d - lo], 1u);
            }
        }
    }
    __syncthreads();
    unsigned* part = partial + (size_t)p * (2 * N) + (size_t)rel * N + lo;
    for (int j = tid; j < nbins; j += 256) part[j] = hist_[j];
}

// ---- wh_r = bf16(x) @ W_r + b_r (both rels) -- PURE, no edge work ----
// Block 256 = 4 waves; wave owns 16 rows; block 64 rows. No LDS for W:
// bfrags are wave-uniform coalesced 1KB global loads from wtf (L1-hit).
// x read once per block (both rels share the A-slice in VGPRs).
__global__ __launch_bounds__(256) void gemm_wh_kernel(
    const float* __restrict__ x, const __bf16* __restrict__ wtf,
    const float* __restrict__ b0, const float* __restrict__ b1,
    const float* __restrict__ a0, const float* __restrict__ a1,
    __bf16* __restrict__ wh, float* __restrict__ s_src,
    float* __restrict__ s_dst, int N)
{
    __shared__ __align__(16) __bf16 Cst[64 * 136];  // 17408 B C-staging
    const int tid = threadIdx.x;

    const int lane = tid & 63;
    const int wave = tid >> 6;
    const int quad = lane >> 4;
    const int mr   = lane & 15;

    const long row0 = (long)blockIdx.x * 64 + wave * 16;
    long arow = row0 + mr;
    if (arow >= N) arow = N - 1;               // clamp; results discarded
    const f32x4* xr = (const f32x4*)(x + arow * DIM);

    // full A slice for this lane: k = ko4*32 + quad*8 .. +7
    bf16x8 afrag[4];
#pragma unroll
    for (int ko4 = 0; ko4 < 4; ++ko4) {
        f32x4 lo = xr[ko4 * 8 + quad * 2], hi = xr[ko4 * 8 + quad * 2 + 1];
        afrag[ko4] = (bf16x8){ (__bf16)lo.x, (__bf16)lo.y, (__bf16)lo.z, (__bf16)lo.w,
                               (__bf16)hi.x, (__bf16)hi.y, (__bf16)hi.z, (__bf16)hi.w };
    }

    const bf16x8* wt = (const bf16x8*)wtf;

#pragma unroll
    for (int rel = 0; rel < 2; ++rel) {
        f32x4 zero = {0.f, 0.f, 0.f, 0.f};
        f32x4 acc[8];
#pragma unroll
        for (int t = 0; t < 8; ++t) acc[t] = zero;

#pragma unroll
        for (int ko4 = 0; ko4 < 4; ++ko4) {
#pragma unroll
            for (int ct = 0; ct < 8; ++ct) {
                bf16x8 bfrag = wt[((rel * 8 + ct) * 4 + ko4) * 64 + lane];
                acc[ct] = __builtin_amdgcn_mfma_f32_16x16x32_bf16(afrag[ko4], bfrag, acc[ct], 0, 0, 0);
            }
        }

        const float* bias = rel ? b1 : b0;
        const float* a    = rel ? a1 : a0;
        // C/D layout: col = ct*16+mr, row = quad*4+rr [m89-verified]
        float psr[4] = {0.f, 0.f, 0.f, 0.f};
        float pdr[4] = {0.f, 0.f, 0.f, 0.f};
#pragma unroll
        for (int ct = 0; ct < 8; ++ct) {
            const int c = ct * 16 + mr;
            const float bn = bias[c];
            const float asc = a[c], adc = a[DIM + c];
#pragma unroll
            for (int rr = 0; rr < 4; ++rr) {
                const float wv = acc[ct][rr] + bn;
                Cst[(wave * 16 + quad * 4 + rr) * 136 + c] = (__bf16)wv;
                psr[rr] += asc * wv;
                pdr[rr] += adc * wv;
            }
        }
#pragma unroll
        for (int off = 1; off < 16; off <<= 1) {
#pragma unroll
            for (int rr = 0; rr < 4; ++rr) {
                psr[rr] += __shfl_xor(psr[rr], off);
                pdr[rr] += __shfl_xor(pdr[rr], off);
            }
        }
        if (mr == 0) {
#pragma unroll
            for (int rr = 0; rr < 4; ++rr) {
                const long orow = row0 + quad * 4 + rr;
                if (orow < N) {
                    s_src[(size_t)rel * N + orow] = psr[rr];
                    s_dst[(size_t)rel * N + orow] = pdr[rr];
                }
            }
        }
        __syncthreads();                        // staging complete
        // coalesced read-back: 1024 chunks of 16B
#pragma unroll
        for (int i = 0; i < 4; ++i) {
            const int chunk = tid + 256 * i;
            const int row = chunk >> 4, c8 = chunk & 15;
            bf16x8 v = *(const bf16x8*)&Cst[row * 136 + c8 * 8];
            const long grow = (long)blockIdx.x * 64 + row;
            if (grow < N)
                *(bf16x8*)(wh + ((size_t)rel * N + grow) * DIM + c8 * 8) = v;
        }
        __syncthreads();                        // before rel1 re-stages Cst
    }
}

// ---------------- CSR scan pass 1 + in-place partial prefix ----------------
// deg[i] = sum of the NP partials; simultaneously rewrites partial[p][i]
// to the EXCLUSIVE prefix sum over p (so fill needs one gather, not p).
__global__ __launch_bounds__(256) void scanA_kernel(
    unsigned* __restrict__ partial, unsigned* __restrict__ tmp,
    unsigned* __restrict__ bsum, int n)
{
    __shared__ unsigned s[256];
    const int t = threadIdx.x;
    const int i = blockIdx.x * 256 + t;
    unsigned v = 0u;
    if (i < n) {
        unsigned run = 0u;
#pragma unroll
        for (int p = 0; p < NP; ++p) {
            const unsigned c = partial[(size_t)p * n + i];
            partial[(size_t)p * n + i] = run;
            run += c;
        }
        v = run;
    }
    s[t] = v;
    __syncthreads();
#pragma unroll
    for (int off = 1; off < 256; off <<= 1) {
        unsigned add = (t >= off) ? s[t - off] : 0u;
        __syncthreads();
        s[t] += add;
        __syncthreads();
    }
    if (i < n) tmp[i] = s[t] - v;            // exclusive within block
    if (t == 255) bsum[blockIdx.x] = s[t];   // block total
}

// ---- CSR scan pass 2: each block re-scans bsum locally, writes rowptr ----
// nb <= 1024 (782 here); rowptr[n] = total (2E) constant.
__global__ __launch_bounds__(256) void scan2_kernel(
    const unsigned* __restrict__ tmp, const unsigned* __restrict__ bsum,
    unsigned* __restrict__ rowptr, int n, int nb, unsigned total)
{
    __shared__ unsigned s[256];
    __shared__ unsigned ex[1024];
    const int t = threadIdx.x;
    unsigned loc[4], sum = 0u;
#pragma unroll
    for (int k = 0; k < 4; ++k) {
        int idx = t * 4 + k;
        loc[k] = (idx < nb) ? bsum[idx] : 0u;
        sum += loc[k];
    }
    s[t] = sum;
    __syncthreads();
#pragma unroll
    for (int off = 1; off < 256; off <<= 1) {
        unsigned add = (t >= off) ? s[t - off] : 0u;
        __syncthreads();
        s[t] += add;
        __syncthreads();
    }
    unsigned run = s[t] - sum;
#pragma unroll
    for (int k = 0; k < 4; ++k) {
        ex[t * 4 + k] = run;
        run += loc[k];
    }
    __syncthreads();
    const unsigned pref = ex[blockIdx.x];
    const int i = blockIdx.x * 256 + t;
    if (i < n) {
        rowptr[i] = tmp[i] + pref;
        if (i == n - 1) rowptr[n] = total;
    }
}

// ---- CSR build + edge scores: fully atomic-free streaming ----
// slot = rowptr[dst] + partial_prefix[p][dst] + local rank (ONE offset
// gather; partial holds exclusive prefixes after scanA). Chain stays
// independent loads -> expf -> fire-and-forget store.
__global__ __launch_bounds__(256) void fill_kernel(
    const int* __restrict__ src0, const int* __restrict__ dst0,
    const int* __restrict__ src1, const int* __restrict__ dst1,
    const float* __restrict__ s_src, const float* __restrict__ s_dst,
    const unsigned* __restrict__ rowptr, const unsigned* __restrict__ rank,
    const unsigned* __restrict__ partial,
    uint2* __restrict__ sorted, int N, int E)
{
    const int i = blockIdx.x * 256 + threadIdx.x;
    if (i >= E) return;
    const int s0 = src0[i], d0 = dst0[i];
    const int s1 = src1[i], d1 = dst1[i];

    const int chunk = (E + NP - 1) / NP;
    const int p = i / chunk;
    const int n2 = 2 * N;
    const unsigned off0 = partial[(size_t)p * n2 + d0];
    const unsigned off1 = partial[(size_t)p * n2 + N + d1];
    const unsigned p0 = rowptr[d0] + off0 + rank[i];
    const unsigned p1 = rowptr[N + d1] + off1 + rank[E + i];

    float v0 = s_src[s0] + s_dst[d0];
    v0 = v0 > 0.f ? v0 : 0.01f * v0;            // leaky_relu slope 0.01
    const float e0 = __expf(v0);
    float v1 = s_src[N + s1] + s_dst[N + d1];
    v1 = v1 > 0.f ? v1 : 0.01f * v1;
    const float e1 = __expf(v1);

    sorted[p0] = make_uint2((unsigned)s0, __float_as_uint(e0));
    sorted[p1] = make_uint2((unsigned)s1, __float_as_uint(e1));
}

// ---------------- two-pass gather-sum, single accumulator ----------------
// One wave per dst; both rels merged into one virtual edge list (len T).
// Pass 1: lane t reads sorted[t].y (coalesced 8B/lane, 1 round for T<=64),
// wave-reduces l0/l1 (DS pipe), computes inv0/inv1. Pass 2: 4 subgroups x 2
// slots gather wh rows with PRE-normalized weights into ONE accumulator
// (16 FMA/round vs 32 dual-acc); sorted is L1-hot from pass 1. Branchless:
// invalid slots clamp idx to 0 with weight 0. Single 2-level combine, no
// final normalize.
__global__ __launch_bounds__(256) void aggregate_kernel(
    const unsigned* __restrict__ rowptr, const uint2* __restrict__ sorted,
    const __bf16* __restrict__ wh, float* __restrict__ out, int N)
{
    const int tid  = threadIdx.x;
    const int lane = tid & 63;
    const int sub  = lane >> 4;
    const int mr   = lane & 15;
    int d = blockIdx.x * 4 + (tid >> 6);
    if (d >= N) return;
    d = __builtin_amdgcn_readfirstlane(d);      // wave-uniform -> s_loads

    const unsigned beg0 = rowptr[d],     end0 = rowptr[d + 1];
    const unsigned beg1 = rowptr[N + d], end1 = rowptr[N + d + 1];
    const unsigned len0 = end0 - beg0;
    const unsigned T    = len0 + (end1 - beg1);

    // ---- pass 1: denominators ----
    float l0 = 0.f, l1 = 0.f;
    for (unsigned t0 = 0; t0 < T; t0 += 64) {
        const unsigned t = t0 + lane;
        const bool v = t < T;
        const bool r = t >= len0;
        unsigned idx = r ? beg1 + (t - len0) : beg0 + t;
        idx = v ? idx : 0u;
        const float ev = __uint_as_float(sorted[idx].y);
        l0 += (v && !r) ? ev : 0.f;
        l1 += (v &&  r) ? ev : 0.f;
    }
#pragma unroll
    for (int off = 1; off < 64; off <<= 1) {
        l0 += __shfl_xor(l0, off);
        l1 += __shfl_xor(l1, off);
    }
    const float inv0 = l0 > 0.f ? 1.f / l0 : 0.f;
    const float inv1 = l1 > 0.f ? 1.f / l1 : 0.f;

    // ---- pass 2: pre-normalized weighted gather ----
    float o[8];
#pragma unroll
    for (int k = 0; k < 8; ++k) o[k] = 0.f;

    const __bf16* __restrict__ wh1 = wh + (size_t)N * DIM;

    for (unsigned t0 = 0; t0 < T; t0 += 8) {
        const unsigned tA = t0 + sub, tB = tA + 4;
        const bool vA = tA < T, vB = tB < T;
        const bool rA = tA >= len0, rB = tB >= len0;

        unsigned iA = rA ? beg1 + (tA - len0) : beg0 + tA;
        unsigned iB = rB ? beg1 + (tB - len0) : beg0 + tB;
        iA = vA ? iA : 0u;
        iB = vB ? iB : 0u;

        const uint2 eA = sorted[iA];
        const uint2 eB = sorted[iB];

        const float wgtA = vA ? __uint_as_float(eA.y) * (rA ? inv1 : inv0) : 0.f;
        const float wgtB = vB ? __uint_as_float(eB.y) * (rB ? inv1 : inv0) : 0.f;

        const bf16x8 wA = *(const bf16x8*)((rA ? wh1 : wh)
                                           + (size_t)eA.x * DIM + mr * 8);
        const bf16x8 wB = *(const bf16x8*)((rB ? wh1 : wh)
                                           + (size_t)eB.x * DIM + mr * 8);
#pragma unroll
        for (int k = 0; k < 8; ++k)
            o[k] += wgtA * (float)wA[k] + wgtB * (float)wB[k];
    }

    // single combine across 4 subgroups
#pragma unroll
    for (int k = 0; k < 8; ++k) {
        o[k] += __shfl_xor(o[k], 16);
        o[k] += __shfl_xor(o[k], 32);
    }

    if (sub == 0) {                             // 16 lanes cover the 512B row
        float4 v0 = {o[0], o[1], o[2], o[3]};
        float4 v1 = {o[4], o[5], o[6], o[7]};
        float* op = out + (size_t)d * DIM + mr * 8;
        *(float4*)op       = v0;
        *(float4*)(op + 4) = v1;
    }
}

extern "C" void kernel_launch(void* const* d_in, const int* in_sizes, int n_in,
                              void* d_out, int out_size, void* d_ws, size_t ws_size,
                              hipStream_t stream) {
    const float* x = (const float*)d_in[0];
    const int* srcs[2] = {(const int*)d_in[1], (const int*)d_in[3]};
    const int* dsts[2] = {(const int*)d_in[2], (const int*)d_in[4]};
    const float* Ws[2] = {(const float*)d_in[5], (const float*)d_in[8]};
    const float* Bs[2] = {(const float*)d_in[6], (const float*)d_in[9]};
    const float* As[2] = {(const float*)d_in[7], (const float*)d_in[10]};

    const int N = in_sizes[0] / DIM;
    const int E = in_sizes[1];
    const int n2 = 2 * N;
    const int nb = (n2 + 255) / 256;            // scan blocks (782)
    float* out = (float*)d_out;

    // workspace carve-up (~70 MB); all chunks 8B-aligned
    char* p = (char*)d_ws;
    __bf16*   wh      = (__bf16*)p;   p += (size_t)n2 * DIM * 2;       // wh0|wh1
    __bf16*   wtf     = (__bf16*)p;   p += (size_t)4096 * 8 * 2;       // 64KB frag-W
    float*    s_src   = (float*)p;    p += (size_t)n2 * 4;
    float*    s_dst   = (float*)p;    p += (size_t)n2 * 4;
    unsigned* partial = (unsigned*)p; p += (size_t)NP * n2 * 4;        // 6.4MB hists
    unsigned* tmp     = (unsigned*)p; p += (size_t)n2 * 4;
    unsigned* rowptr  = (unsigned*)p; p += (size_t)(n2 + 2) * 4;       // pad to 8B
    unsigned* rank    = (unsigned*)p; p += (size_t)2 * E * 4;          // per-edge rank
    uint2*    sorted  = (uint2*)p;    p += (size_t)2 * E * 8;          // {src, e}
    unsigned* bsum    = (unsigned*)p; p += (size_t)nb * 4;

    // rank histograms + W-fragment prep in one dispatch (independent roles)
    rank_prep_kernel<<<RANK_BLOCKS + 16, 256, 0, stream>>>(
        dsts[0], dsts[1], partial, rank, Ws[0], Ws[1], wtf, N, E);
    gemm_wh_kernel<<<(N + 63) / 64, 256, 0, stream>>>(
        x, wtf, Bs[0], Bs[1], As[0], As[1], wh, s_src, s_dst, N);
    scanA_kernel<<<nb, 256, 0, stream>>>(partial, tmp, bsum, n2);
    scan2_kernel<<<nb, 256, 0, stream>>>(tmp, bsum, rowptr, n2, nb,
                                         (unsigned)(2 * E));
    fill_kernel<<<(E + 255) / 256, 256, 0, stream>>>(
        srcs[0], dsts[0], srcs[1], dsts[1], s_src, s_dst,
        rowptr, rank, partial, sorted, N, E);
    aggregate_kernel<<<(N + 3) / 4, 256, 0, stream>>>(
        rowptr, sorted, wh, out, N);
}